// Round 4
// baseline (555.090 us; speedup 1.0000x reference)
//
#include <hip/hip_runtime.h>
#include <hip/hip_cooperative_groups.h>
#include <math.h>

namespace cg = cooperative_groups;

#define NB 4096
#define NN 10000
#define ND 256
#define ALPHA 0.2f
#define CS 16                 // rows per chunk
#define NG (NN / CS)          // 625 chunks (exact)
#define SCHUNK 25             // chunks per superchunk
#define NSUPER (NG / SCHUNK)  // 25 superchunks (exact)
#define MSEGS 26
#define NTILES ((NN + 255) / 256)              // 40
#define SEGLEN ((NN + MSEGS - 1) / MSEGS)      // 385 (385*26 >= 10000)

// One cooperative kernel, 6 phases separated by grid.sync():
//  A: zero accumulators; dot scores t_n = V[n]·Wn, s_b = P[b]·Wp (wave/row)
//  B: counting-sort ranks (1040 balanced units, LDS-tiled)
//  C: scatter to sorted order + exp factors
//  D: per-chunk sums (+atomic superchunk sums); per-b binary searches (kk[b])
//  E: parallel exclusive scan over 25 superchunks (26 independent blocks)
//  F: finalize — superchunk prefix + <=24 chunk rows + <=15 V rows, epilogue
__global__ __launch_bounds__(256, 1) void k_fused(
    const float* __restrict__ P, const float* __restrict__ V,
    const float* __restrict__ K, float* __restrict__ out,
    char* __restrict__ ws) {
  cg::grid_group grid = cg::this_grid();
  const int tid = threadIdx.x;
  const int bid = blockIdx.x;
  const int nb = gridDim.x;
  const int gt = bid * 256 + tid;
  const int nt = nb * 256;

  float* t     = (float*)ws;
  float* s     = t + NN;
  int*   rank  = (int*)(s + NB);
  float* tsort = (float*)(rank + NN);
  float* eA    = tsort + NN;
  float* eC    = eA + NN;
  int*   idxs  = (int*)(eC + NN);
  int*   kk    = idxs + NN;
  float* SA    = (float*)(kk + NB);
  float* SC    = SA + (size_t)NG * ND;
  float* sa0   = SC + (size_t)NG * ND;
  float* sc0   = sa0 + NG;
  float* SSA   = sc0 + NG;
  float* SSC   = SSA + NSUPER * ND;
  float* ssa0  = SSC + NSUPER * ND;
  float* ssc0  = ssa0 + NSUPER;
  float* PSA   = ssc0 + NSUPER;
  float* PSC   = PSA + (NSUPER + 1) * ND;
  float* Psa0  = PSC + (NSUPER + 1) * ND;
  float* Psc0  = Psa0 + (NSUPER + 1);

  __shared__ float sm[256];

  // ---- Phase A: zero atomic accumulators; dot scores ----
  for (int i = gt; i < NN; i += nt) rank[i] = 0;
  for (int i = gt; i < NSUPER * ND; i += nt) { SSA[i] = 0.f; SSC[i] = 0.f; }
  for (int i = gt; i < NSUPER; i += nt) { ssa0[i] = 0.f; ssc0[i] = 0.f; }
  {
    int lane = tid & 63;
    int wid = gt >> 6;
    int nw = nt >> 6;
    for (int j = wid; j < NN + NB; j += nw) {
      const float* row; const float* wv; float* outp; int oi;
      if (j < NN) { row = V + (size_t)j * ND; wv = K + ND; outp = t; oi = j; }
      else        { row = P + (size_t)(j - NN) * ND; wv = K; outp = s; oi = j - NN; }
      float4 r  = ((const float4*)row)[lane];
      float4 kx = ((const float4*)wv)[lane];
      float acc = r.x * kx.x + r.y * kx.y + r.z * kx.z + r.w * kx.w;
      #pragma unroll
      for (int off = 32; off; off >>= 1) acc += __shfl_down(acc, off, 64);
      if (lane == 0) outp[oi] = acc;
    }
  }
  grid.sync();

  // ---- Phase B: ranks. rank_n = #{m : t_m < t_n or (t_m==t_n and m<n)} ----
  for (int u = bid; u < NTILES * MSEGS; u += nb) {
    int ntile = u / MSEGS, seg = u % MSEGS;
    int n = ntile * 256 + tid;
    float tn = (n < NN) ? t[n] : 0.f;
    int m0 = seg * SEGLEN, m1 = min(NN, m0 + SEGLEN);
    int r = 0;
    for (int k0 = m0; k0 < m1; k0 += 256) {
      __syncthreads();                      // protect sm reuse
      int m = k0 + tid;
      sm[tid] = (m < m1) ? t[m] : 0.f;
      __syncthreads();
      int lim = min(256, m1 - k0);
      for (int j = 0; j < lim; ++j) {
        float tm = sm[j];
        r += (tm < tn || (tm == tn && (k0 + j) < n)) ? 1 : 0;
      }
    }
    if (n < NN && r) atomicAdd(&rank[n], r);
  }
  grid.sync();

  // ---- Phase C: scatter + exp factors ----
  for (int n = gt; n < NN; n += nt) {
    int r = rank[n];
    float tn = t[n];
    tsort[r] = tn;
    eA[r] = __expf(tn);
    eC[r] = __expf(ALPHA * tn);
    idxs[r] = n;
  }
  grid.sync();

  // ---- Phase D: chunk sums (+superchunk atomics); per-b binary searches ----
  for (int g = bid; g < NG; g += nb) {
    int d = tid;
    int base = g * CS;
    float accA = 0.f, accC = 0.f, sa = 0.f, sc = 0.f;
    #pragma unroll
    for (int j = 0; j < CS; ++j) {
      int i = base + j;
      float ea = eA[i], ec = eC[i];
      float v = V[(size_t)idxs[i] * ND + d];
      accA += ea * v; accC += ec * v;
      sa += ea; sc += ec;
    }
    SA[(size_t)g * ND + d] = accA;
    SC[(size_t)g * ND + d] = accC;
    int gs = g / SCHUNK;
    atomicAdd(&SSA[(size_t)gs * ND + d], accA);
    atomicAdd(&SSC[(size_t)gs * ND + d], accC);
    if (d == 0) {
      sa0[g] = sa; sc0[g] = sc;
      atomicAdd(&ssa0[gs], sa);
      atomicAdd(&ssc0[gs], sc);
    }
  }
  for (int b = gt; b < NB; b += nt) {
    float key = -s[b];
    int lo = 0, hi = NN;   // lower_bound: first idx with tsort[idx] >= key
    while (lo < hi) {
      int mid = (lo + hi) >> 1;
      if (tsort[mid] < key) lo = mid + 1; else hi = mid;
    }
    kk[b] = lo;
  }
  grid.sync();

  // ---- Phase E: exclusive scan over superchunks (26 independent rows) ----
  for (int gs = bid; gs <= NSUPER; gs += nb) {
    int d = tid;
    float aA = 0.f, aC = 0.f;
    for (int g = 0; g < gs; ++g) {
      aA += SSA[(size_t)g * ND + d];
      aC += SSC[(size_t)g * ND + d];
    }
    PSA[(size_t)gs * ND + d] = aA;
    PSC[(size_t)gs * ND + d] = aC;
    if (d == 0) {
      float a0 = 0.f, c0 = 0.f;
      for (int g = 0; g < gs; ++g) { a0 += ssa0[g]; c0 += ssc0[g]; }
      Psa0[gs] = a0; Psc0[gs] = c0;
    }
  }
  grid.sync();

  // ---- Phase F: finalize ----
  for (int b = bid; b < NB; b += nb) {
    int d = tid;
    int k = kk[b];
    int g = k >> 4;          // chunk idx; k==NN -> g==NG
    int gs = g / SCHUNK;     // superchunk idx; g==NG -> gs==NSUPER
    float prefA = PSA[(size_t)gs * ND + d];
    float prefC = PSC[(size_t)gs * ND + d];
    float pa = Psa0[gs], pc = Psc0[gs];
    for (int j = gs * SCHUNK; j < g; ++j) {
      prefA += SA[(size_t)j * ND + d];
      prefC += SC[(size_t)j * ND + d];
      pa += sa0[j]; pc += sc0[j];
    }
    for (int i = g << 4; i < k; ++i) {
      float ea = eA[i], ec = eC[i];
      float v = V[(size_t)idxs[i] * ND + d];
      prefA += ea * v; prefC += ec * v;
      pa += ea; pc += ec;
    }
    float totA = PSA[(size_t)NSUPER * ND + d];
    float ta0 = Psa0[NSUPER];
    float sb = s[b];
    float ea = __expf(sb), ec = __expf(ALPHA * sb);
    float l = ea * (ta0 - pa) + ec * pc;
    float agg = (ea * (totA - prefA) + ec * prefC) / l;
    out[(size_t)b * ND + d] = P[(size_t)b * ND + d] + agg;
  }
}

extern "C" void kernel_launch(void* const* d_in, const int* in_sizes, int n_in,
                              void* d_out, int out_size, void* d_ws, size_t ws_size,
                              hipStream_t stream) {
  const float* P = (const float*)d_in[0];   // (B, D)
  const float* V = (const float*)d_in[1];   // (N, D)
  const float* K = (const float*)d_in[2];   // (2D, 1)
  float* out = (float*)d_out;
  char* ws = (char*)d_ws;

  int blocks_per_cu = 0;
  (void)hipOccupancyMaxActiveBlocksPerMultiprocessor(&blocks_per_cu,
                                                     (const void*)k_fused, 256, 0);
  if (blocks_per_cu < 1) blocks_per_cu = 1;
  int grid = blocks_per_cu * 256;
  if (grid > NTILES * MSEGS) grid = NTILES * MSEGS;   // 1040: rank-phase balance

  void* args[] = {(void*)&P, (void*)&V, (void*)&K, (void*)&out, (void*)&ws};
  (void)hipLaunchCooperativeKernel((const void*)k_fused, dim3(grid), dim3(256),
                                   args, 0, stream);
}

// Round 5
// 127.766 us; speedup vs baseline: 4.3446x; 4.3446x over previous
//
#include <hip/hip_runtime.h>
#include <math.h>

#define NB 4096
#define NN 10000
#define ND 256
#define ALPHA 0.2f
#define CS 16                 // rows per chunk
#define NG (NN / CS)          // 625 chunks (exact)
#define SCHUNK 25             // chunks per superchunk
#define NSUPER (NG / SCHUNK)  // 25 superchunks (exact)
#define MSEGS 26
#define SEGLEN ((NN + MSEGS - 1) / MSEGS)   // 385
#define ZELEMS (NN + 2 * NSUPER * ND + 2 * NSUPER)  // rank + SSA + SSC + ssa0 + ssc0

typedef unsigned long long u64;

// --- 1) dot scores t_n=V[n]·Wn, s_b=P[b]·Wp (one wave per row); sortable
// u64 keys tk[n] (strict total order: float-monotone uint32 <<14 | index);
// zero the atomic accumulator region.
__global__ __launch_bounds__(256) void k_dot(
    const float* __restrict__ P, const float* __restrict__ V,
    const float* __restrict__ K,
    float* __restrict__ t, float* __restrict__ s, u64* __restrict__ tk,
    int* __restrict__ zero_region) {
  int gt = blockIdx.x * 256 + threadIdx.x;
  if (gt < ZELEMS) zero_region[gt] = 0;
  int j = blockIdx.x * 4 + (threadIdx.x >> 6);
  int lane = threadIdx.x & 63;
  if (j >= NN + NB) return;
  const float* row; const float* wv; int oi; bool isn;
  if (j < NN) { row = V + (size_t)j * ND; wv = K + ND; oi = j; isn = true; }
  else        { row = P + (size_t)(j - NN) * ND; wv = K; oi = j - NN; isn = false; }
  float4 r  = ((const float4*)row)[lane];
  float4 kx = ((const float4*)wv)[lane];
  float acc = r.x * kx.x + r.y * kx.y + r.z * kx.z + r.w * kx.w;
  #pragma unroll
  for (int off = 32; off; off >>= 1) acc += __shfl_down(acc, off, 64);
  if (lane == 0) {
    if (isn) {
      t[oi] = acc;
      unsigned bits = __float_as_uint(acc);
      unsigned key = bits ^ (((int)bits >> 31) | 0x80000000u);  // monotone map
      tk[oi] = ((u64)key << 14) | (unsigned)oi;
    } else {
      s[oi] = acc;
    }
  }
}

// --- 2) rank[n] = #{m : tk[m] < tk[n]} via wave-uniform key loads (no LDS).
__global__ __launch_bounds__(256) void k_rank(
    const u64* __restrict__ tk, int* __restrict__ rank) {
  int n = blockIdx.x * 256 + threadIdx.x;
  u64 kn = (n < NN) ? tk[n] : ~0ull;
  int m0 = blockIdx.y * SEGLEN;
  int m1 = min(NN, m0 + SEGLEN);
  int r = 0;
  int m = m0;
  #pragma unroll 1
  for (; m + 4 <= m1; m += 4) {
    u64 a = tk[m], b2 = tk[m + 1], c = tk[m + 2], dd = tk[m + 3];
    r += (a < kn) + (b2 < kn) + (c < kn) + (dd < kn);
  }
  for (; m < m1; ++m) r += (tk[m] < kn);
  if (n < NN && r) atomicAdd(&rank[n], r);
}

// --- 3) scatter into sorted order + exp factors.
__global__ __launch_bounds__(256) void k_scatter(
    const float* __restrict__ t, const int* __restrict__ rank,
    float* __restrict__ tsort, float* __restrict__ eA, float* __restrict__ eC,
    int* __restrict__ idxs) {
  int n = blockIdx.x * 256 + threadIdx.x;
  if (n < NN) {
    int r = rank[n];
    float tn = t[n];
    tsort[r] = tn;
    eA[r] = __expf(tn);
    eC[r] = __expf(ALPHA * tn);
    idxs[r] = n;
  }
}

// --- 4) blocks <NG: per-chunk sums + atomic superchunk sums.
//        blocks >=NG (16 of them): per-patient binary searches -> kk[b].
__global__ __launch_bounds__(256) void k_chunk(
    const float* __restrict__ eA, const float* __restrict__ eC,
    const int* __restrict__ idxs, const float* __restrict__ V,
    const float* __restrict__ s, const float* __restrict__ tsort,
    float* __restrict__ SA, float* __restrict__ SC,
    float* __restrict__ sa0, float* __restrict__ sc0,
    float* __restrict__ SSA, float* __restrict__ SSC,
    float* __restrict__ ssa0, float* __restrict__ ssc0,
    int* __restrict__ kk) {
  int g = blockIdx.x, d = threadIdx.x;
  if (g < NG) {
    int base = g * CS;
    float accA = 0.f, accC = 0.f, sa = 0.f, sc = 0.f;
    #pragma unroll
    for (int j = 0; j < CS; ++j) {
      int i = base + j;
      float ea = eA[i], ec = eC[i];
      float v = V[(size_t)idxs[i] * ND + d];
      accA += ea * v; accC += ec * v;
      sa += ea; sc += ec;
    }
    SA[(size_t)g * ND + d] = accA;
    SC[(size_t)g * ND + d] = accC;
    int gs = g / SCHUNK;
    atomicAdd(&SSA[(size_t)gs * ND + d], accA);
    atomicAdd(&SSC[(size_t)gs * ND + d], accC);
    if (d == 0) {
      sa0[g] = sa; sc0[g] = sc;
      atomicAdd(&ssa0[gs], sa);
      atomicAdd(&ssc0[gs], sc);
    }
  } else {
    int b = (g - NG) * 256 + d;           // 16 blocks x 256 = 4096 = NB
    float key = -s[b];
    int lo = 0, hi = NN;  // lower_bound: first idx with tsort[idx] >= key
    while (lo < hi) {
      int mid = (lo + hi) >> 1;
      if (tsort[mid] < key) lo = mid + 1; else hi = mid;
    }
    kk[b] = lo;
  }
}

// --- 5) finalize: A-side as suffix sums, C-side as prefix sums (25 SS rows
// + <=24 chunk rows + <=15 V rows per block), fused epilogue.
__global__ __launch_bounds__(256) void k_finalize(
    const float* __restrict__ P, const float* __restrict__ V,
    const float* __restrict__ s, const int* __restrict__ kk,
    const float* __restrict__ eA, const float* __restrict__ eC,
    const int* __restrict__ idxs,
    const float* __restrict__ SA, const float* __restrict__ SC,
    const float* __restrict__ sa0, const float* __restrict__ sc0,
    const float* __restrict__ SSA, const float* __restrict__ SSC,
    const float* __restrict__ ssa0, const float* __restrict__ ssc0,
    float* __restrict__ out) {
  int b = blockIdx.x, d = threadIdx.x;
  int k = kk[b];
  int g = k >> 4;          // chunk idx; k==NN -> g==NG
  int gs = g / SCHUNK;     // superchunk idx; g==NG -> gs==NSUPER
  float suffA = 0.f, prefC = 0.f, suffa = 0.f, prefc = 0.f;
  for (int q = gs; q < NSUPER; ++q) {
    suffA += SSA[(size_t)q * ND + d];
    suffa += ssa0[q];
  }
  for (int q = 0; q < gs; ++q) {
    prefC += SSC[(size_t)q * ND + d];
    prefc += ssc0[q];
  }
  for (int j = gs * SCHUNK; j < g; ++j) {
    suffA -= SA[(size_t)j * ND + d];
    prefC += SC[(size_t)j * ND + d];
    suffa -= sa0[j];
    prefc += sc0[j];
  }
  for (int i = g << 4; i < k; ++i) {
    float ea = eA[i], ec = eC[i];
    float v = V[(size_t)idxs[i] * ND + d];
    suffA -= ea * v; prefC += ec * v;
    suffa -= ea;     prefc += ec;
  }
  float sb = s[b];
  float ea = __expf(sb), ec = __expf(ALPHA * sb);
  float l = ea * suffa + ec * prefc;
  float agg = (ea * suffA + ec * prefC) / l;
  out[(size_t)b * ND + d] = P[(size_t)b * ND + d] + agg;
}

extern "C" void kernel_launch(void* const* d_in, const int* in_sizes, int n_in,
                              void* d_out, int out_size, void* d_ws, size_t ws_size,
                              hipStream_t stream) {
  const float* P = (const float*)d_in[0];   // (B, D)
  const float* V = (const float*)d_in[1];   // (N, D)
  const float* K = (const float*)d_in[2];   // (2D, 1)
  float* out = (float*)d_out;

  char* w = (char*)d_ws;
  u64*   tk    = (u64*)w;   w += sizeof(u64) * NN;        // 8B-aligned first
  // --- zeroed-by-k_dot region (contiguous): rank, SSA, SSC, ssa0, ssc0 ---
  int*   zreg  = (int*)w;
  int*   rank  = (int*)w;   w += sizeof(int) * NN;
  float* SSA   = (float*)w; w += sizeof(float) * NSUPER * ND;
  float* SSC   = (float*)w; w += sizeof(float) * NSUPER * ND;
  float* ssa0  = (float*)w; w += sizeof(float) * NSUPER;
  float* ssc0  = (float*)w; w += sizeof(float) * NSUPER;
  // --- rest ---
  float* t     = (float*)w; w += sizeof(float) * NN;
  float* s     = (float*)w; w += sizeof(float) * NB;
  float* tsort = (float*)w; w += sizeof(float) * NN;
  float* eA    = (float*)w; w += sizeof(float) * NN;
  float* eC    = (float*)w; w += sizeof(float) * NN;
  int*   idxs  = (int*)w;   w += sizeof(int) * NN;
  int*   kk    = (int*)w;   w += sizeof(int) * NB;
  float* SA    = (float*)w; w += sizeof(float) * (size_t)NG * ND;
  float* SC    = (float*)w; w += sizeof(float) * (size_t)NG * ND;
  float* sa0   = (float*)w; w += sizeof(float) * NG;
  float* sc0   = (float*)w; w += sizeof(float) * NG;

  k_dot<<<(NN + NB + 3) / 4, 256, 0, stream>>>(P, V, K, t, s, tk, zreg);
  k_rank<<<dim3((NN + 255) / 256, MSEGS), 256, 0, stream>>>(tk, rank);
  k_scatter<<<(NN + 255) / 256, 256, 0, stream>>>(t, rank, tsort, eA, eC, idxs);
  k_chunk<<<NG + NB / 256, 256, 0, stream>>>(eA, eC, idxs, V, s, tsort,
                                             SA, SC, sa0, sc0,
                                             SSA, SSC, ssa0, ssc0, kk);
  k_finalize<<<NB, 256, 0, stream>>>(P, V, s, kk, eA, eC, idxs,
                                     SA, SC, sa0, sc0, SSA, SSC, ssa0, ssc0, out);
}